// Round 8
// baseline (904.819 us; speedup 1.0000x reference)
//
#include <hip/hip_runtime.h>
#include <hip/hip_bf16.h>
#include <cstdint>
#include <cstddef>

#define N_NODES 65536
#define N_EDGES 1048576
#define N_GRAPHS 128
#define NPG 512
#define IN_DIM 64
#define HID 128
#define BN_EPS 1e-5f

typedef __attribute__((ext_vector_type(8))) short bf16x8;
typedef __attribute__((ext_vector_type(4))) float f32x4;
typedef __attribute__((ext_vector_type(8))) unsigned short u16x8;
typedef __attribute__((ext_vector_type(4))) unsigned short u16x4;

// ---- bf16 helpers (RNE, matches v_cvt) ----
__device__ inline unsigned short f2bf(float f) {
  unsigned u = __builtin_bit_cast(unsigned, f);
  u = u + 0x7fffu + ((u >> 16) & 1u);
  return (unsigned short)(u >> 16);
}
__device__ inline float bf2f(unsigned short h) {
  unsigned u = ((unsigned)h) << 16;
  return __builtin_bit_cast(float, u);
}
__device__ inline void split_bf(float v, unsigned short& hi, unsigned short& lo) {
  hi = f2bf(v);
  lo = f2bf(v - bf2f(hi));
}
// 8-B-aligned LDS fragment load (two ds_read_b64) — rows stride 36 u16 = 72 B
__device__ inline bf16x8 ld_bf8(const unsigned short* p) {
  u16x4 a = *(const u16x4*)p;
  u16x4 b = *(const u16x4*)(p + 4);
  u16x8 r = __builtin_shufflevector(a, b, 0, 1, 2, 3, 4, 5, 6, 7);
  return __builtin_bit_cast(bf16x8, r);
}

// ---------------- CSR build ----------------
__global__ __launch_bounds__(256) void hist_kernel(const int* __restrict__ dst,
                                                   int* __restrict__ deg) {
  int e = blockIdx.x * 256 + threadIdx.x;
  if (e < N_EDGES) atomicAdd(&deg[dst[e]], 1);
}

__global__ __launch_bounds__(256) void dis_kernel(const int* __restrict__ deg,
                                                  float* __restrict__ dis) {
  int n = blockIdx.x * 256 + threadIdx.x;
  if (n < N_NODES) dis[n] = 1.0f / sqrtf((float)deg[n] + 1.0f);
}

__global__ __launch_bounds__(1024) void scan_kernel(const int* __restrict__ deg,
                                                    int* __restrict__ offsets,
                                                    int* __restrict__ cursor) {
  __shared__ int sums[1024];
  int t = threadIdx.x;
  int base = t * 64;
  const int4* dp = (const int4*)(deg + base);
  int s = 0;
#pragma unroll
  for (int i = 0; i < 16; i++) {
    int4 v = dp[i];
    s += v.x + v.y + v.z + v.w;
  }
  sums[t] = s;
  __syncthreads();
  for (int off = 1; off < 1024; off <<= 1) {
    int v = (t >= off) ? sums[t - off] : 0;
    __syncthreads();
    sums[t] += v;
    __syncthreads();
  }
  int run = (t == 0) ? 0 : sums[t - 1];
#pragma unroll
  for (int i = 0; i < 16; i++) {
    int4 v = dp[i];
    int idx = base + i * 4;
    offsets[idx] = run; cursor[idx] = run; run += v.x;
    offsets[idx + 1] = run; cursor[idx + 1] = run; run += v.y;
    offsets[idx + 2] = run; cursor[idx + 2] = run; run += v.z;
    offsets[idx + 3] = run; cursor[idx + 3] = run; run += v.w;
  }
  if (t == 1023) offsets[N_NODES] = run;
}

__global__ __launch_bounds__(256) void fill_kernel(const int* __restrict__ src,
                                                   const int* __restrict__ dst,
                                                   int* __restrict__ cursor,
                                                   int* __restrict__ csr) {
  int e = blockIdx.x * 256 + threadIdx.x;
  if (e < N_EDGES) {
    int d = dst[e];
    int slot = atomicAdd(&cursor[d], 1);
    csr[slot] = src[e];
  }
}

// ---------------- aggregation: block-per-node, 4 waves split the neighbor list ---------
// 16 gathers in flight per node (vs 4 in R6) to attack gather latency.
__global__ __launch_bounds__(256) void agg64_kernel(const float* __restrict__ x,
                                                    const float* __restrict__ dis,
                                                    const int* __restrict__ offsets,
                                                    const int* __restrict__ csr,
                                                    unsigned short* __restrict__ zhi,
                                                    unsigned short* __restrict__ zlo) {
  int node = blockIdx.x;
  int w = threadIdx.x >> 6;
  int lane = threadIdx.x & 63;
  __shared__ float ps[4][64];
  float dn = dis[node];
  int beg = offsets[node], end = offsets[node + 1];
  float acc = 0.0f;
  if (w == 0) acc = x[(size_t)node * 64 + lane] * dn * dn;
  int deg = end - beg;
  int q = (deg + 3) >> 2;
  int ks = beg + w * q;
  int ke = ks + q;
  if (ke > end) ke = end;
  if (ks > end) ks = end;
  int k = ks;
  for (; k + 4 <= ke; k += 4) {
    int s0 = csr[k], s1 = csr[k + 1], s2 = csr[k + 2], s3 = csr[k + 3];
    float w0 = dn * dis[s0], w1 = dn * dis[s1], w2 = dn * dis[s2], w3 = dn * dis[s3];
    float v0 = x[(size_t)s0 * 64 + lane];
    float v1 = x[(size_t)s1 * 64 + lane];
    float v2 = x[(size_t)s2 * 64 + lane];
    float v3 = x[(size_t)s3 * 64 + lane];
    acc = fmaf(w0, v0, acc);
    acc = fmaf(w1, v1, acc);
    acc = fmaf(w2, v2, acc);
    acc = fmaf(w3, v3, acc);
  }
  for (; k < ke; k++) {
    int s = csr[k];
    acc = fmaf(dn * dis[s], x[(size_t)s * 64 + lane], acc);
  }
  ps[w][lane] = acc;
  __syncthreads();
  if (threadIdx.x < 64) {
    int d = threadIdx.x;
    float v = (ps[0][d] + ps[1][d]) + (ps[2][d] + ps[3][d]);
    unsigned short h_, l_;
    split_bf(v, h_, l_);
    zhi[(size_t)node * 64 + d] = h_;
    zlo[(size_t)node * 64 + d] = l_;
  }
}

__global__ __launch_bounds__(256) void agg128_kernel(const float* __restrict__ h,
                                                     const float* __restrict__ dis,
                                                     const int* __restrict__ offsets,
                                                     const int* __restrict__ csr,
                                                     unsigned short* __restrict__ zhi,
                                                     unsigned short* __restrict__ zlo) {
  int node = blockIdx.x;
  int w = threadIdx.x >> 6;
  int lane = threadIdx.x & 63;
  __shared__ float ps[4][128];
  float dn = dis[node];
  int beg = offsets[node], end = offsets[node + 1];
  float a0 = 0.0f, a1 = 0.0f;
  if (w == 0) {
    float sn = dn * dn;
    const float* hr = h + (size_t)node * 128;
    a0 = hr[lane] * sn;
    a1 = hr[lane + 64] * sn;
  }
  int deg = end - beg;
  int q = (deg + 3) >> 2;
  int ks = beg + w * q;
  int ke = ks + q;
  if (ke > end) ke = end;
  if (ks > end) ks = end;
  int k = ks;
  for (; k + 4 <= ke; k += 4) {
    int s0 = csr[k], s1 = csr[k + 1], s2 = csr[k + 2], s3 = csr[k + 3];
    float w0 = dn * dis[s0], w1 = dn * dis[s1], w2 = dn * dis[s2], w3 = dn * dis[s3];
    const float* p0 = h + (size_t)s0 * 128;
    const float* p1 = h + (size_t)s1 * 128;
    const float* p2 = h + (size_t)s2 * 128;
    const float* p3 = h + (size_t)s3 * 128;
    float u0 = p0[lane], d0 = p0[lane + 64];
    float u1 = p1[lane], d1 = p1[lane + 64];
    float u2 = p2[lane], d2 = p2[lane + 64];
    float u3 = p3[lane], d3 = p3[lane + 64];
    a0 = fmaf(w0, u0, a0); a1 = fmaf(w0, d0, a1);
    a0 = fmaf(w1, u1, a0); a1 = fmaf(w1, d1, a1);
    a0 = fmaf(w2, u2, a0); a1 = fmaf(w2, d2, a1);
    a0 = fmaf(w3, u3, a0); a1 = fmaf(w3, d3, a1);
  }
  for (; k < ke; k++) {
    int s = csr[k];
    float wt = dn * dis[s];
    const float* hs = h + (size_t)s * 128;
    a0 = fmaf(wt, hs[lane], a0);
    a1 = fmaf(wt, hs[lane + 64], a1);
  }
  ps[w][lane] = a0;
  ps[w][lane + 64] = a1;
  __syncthreads();
  if (threadIdx.x < 128) {
    int d = threadIdx.x;
    float v = (ps[0][d] + ps[1][d]) + (ps[2][d] + ps[3][d]);
    unsigned short h_, l_;
    split_bf(v, h_, l_);
    zhi[(size_t)node * 128 + d] = h_;
    zlo[(size_t)node * 128 + d] = l_;
  }
}

// ---------------- weight prep: fp32 W -> bf16 hi/lo in b-fragment layout ----------------
template <bool TRANS>
__global__ __launch_bounds__(256) void wprep_kernel(const float* __restrict__ W, int K, int O,
                                                    unsigned short* __restrict__ hi,
                                                    unsigned short* __restrict__ lo) {
  int idx = blockIdx.x * 256 + threadIdx.x;
  int KC = K / 32;
  int total = (O / 16) * KC * 64;
  if (idx >= total) return;
  int lane = idx & 63;
  int rest = idx >> 6;
  int kc = rest % KC;
  int nt = rest / KC;
  int n = nt * 16 + (lane & 15);
  int kb = kc * 32 + (lane >> 4) * 8;
  unsigned short* hp = hi + (size_t)idx * 8;
  unsigned short* lp = lo + (size_t)idx * 8;
#pragma unroll
  for (int j = 0; j < 8; j++) {
    int k = kb + j;
    float v = TRANS ? W[(size_t)n * K + k] : W[(size_t)k * O + n];
    unsigned short h_, l_;
    split_bf(v, h_, l_);
    hp[j] = h_;
    lp[j] = l_;
  }
}

// ---------------- MFMA GEMM (3 split-products: hh + hl + lh; ll ~ 2^-17, dropped) ------
template <int K, int O, bool DOBN, bool DORELU, bool SPLIT_OUT>
__global__ __launch_bounds__(256) void gemm_mfma(
    const unsigned short* __restrict__ Ahi, const unsigned short* __restrict__ Alo,
    const unsigned short* __restrict__ Whi, const unsigned short* __restrict__ Wlo,
    const float* __restrict__ bias,
    const float* __restrict__ gamma, const float* __restrict__ beta,
    const float* __restrict__ mean, const float* __restrict__ var,
    float* __restrict__ Cf, unsigned short* __restrict__ Chi,
    unsigned short* __restrict__ Clo) {
  constexpr int KC = K / 32;
  int wave = threadIdx.x >> 6;
  int lane = threadIdx.x & 63;
  int m0 = blockIdx.x * 128 + wave * 32;
  int o0 = blockIdx.y * 128;
  int mrow = lane & 15;
  int kseg = (lane >> 4) * 8;

  f32x4 acc[2][8];
#pragma unroll
  for (int mt = 0; mt < 2; mt++)
#pragma unroll
    for (int nt = 0; nt < 8; nt++) acc[mt][nt] = (f32x4)0.0f;

#pragma unroll
  for (int kc = 0; kc < KC; kc++) {
    bf16x8 ah[2], al[2];
#pragma unroll
    for (int mt = 0; mt < 2; mt++) {
      size_t aoff = (size_t)(m0 + mt * 16 + mrow) * K + kc * 32 + kseg;
      ah[mt] = *(const bf16x8*)(Ahi + aoff);
      al[mt] = *(const bf16x8*)(Alo + aoff);
    }
#pragma unroll
    for (int nt = 0; nt < 8; nt++) {
      size_t foff = (((size_t)(blockIdx.y * 8 + nt) * KC + kc) * 64 + lane) * 8;
      bf16x8 bh = *(const bf16x8*)(Whi + foff);
      bf16x8 bl = *(const bf16x8*)(Wlo + foff);
#pragma unroll
      for (int mt = 0; mt < 2; mt++) {
        acc[mt][nt] = __builtin_amdgcn_mfma_f32_16x16x32_bf16(ah[mt], bh, acc[mt][nt], 0, 0, 0);
        acc[mt][nt] = __builtin_amdgcn_mfma_f32_16x16x32_bf16(ah[mt], bl, acc[mt][nt], 0, 0, 0);
        acc[mt][nt] = __builtin_amdgcn_mfma_f32_16x16x32_bf16(al[mt], bh, acc[mt][nt], 0, 0, 0);
      }
    }
  }

  int ccol = lane & 15;
  int crow0 = (lane >> 4) * 4;
#pragma unroll
  for (int nt = 0; nt < 8; nt++) {
    int c = o0 + nt * 16 + ccol;
    float sc, cb;
    float b = bias[c];
    if (DOBN) {
      sc = gamma[c] * rsqrtf(var[c] + BN_EPS);
      cb = (b - mean[c]) * sc + beta[c];
    } else {
      sc = 1.0f;
      cb = b;
    }
#pragma unroll
    for (int mt = 0; mt < 2; mt++) {
#pragma unroll
      for (int r = 0; r < 4; r++) {
        float v = fmaf(acc[mt][nt][r], sc, cb);
        if (DORELU) v = fmaxf(v, 0.0f);
        size_t row = (size_t)(m0 + mt * 16 + crow0 + r);
        if (SPLIT_OUT) {
          unsigned short h_, l_;
          split_bf(v, h_, l_);
          Chi[row * O + c] = h_;
          Clo[row * O + c] = l_;
        } else {
          Cf[row * O + c] = v;
        }
      }
    }
  }
}

// ---------------- key-norm max per (graph, head) ----------------
__global__ __launch_bounds__(256) void knorm_kernel(const float* __restrict__ qkv,
                                                    float* __restrict__ kmax2) {
  int g = blockIdx.x >> 2;
  int h = blockIdx.x & 3;
  size_t gbase = (size_t)g * NPG;
  float best = 0.0f;
#pragma unroll
  for (int r = 0; r < 2; r++) {
    int j = r * 256 + threadIdx.x;
    const float* kp = &qkv[(gbase + j) * 384 + 128 + h * 32];
    float s = 0.0f;
#pragma unroll
    for (int i = 0; i < 8; i++) {
      float4 v = *(const float4*)(kp + i * 4);
      s = fmaf(v.x, v.x, s);
      s = fmaf(v.y, v.y, s);
      s = fmaf(v.z, v.z, s);
      s = fmaf(v.w, v.w, s);
    }
    best = fmaxf(best, s);
  }
#pragma unroll
  for (int off = 32; off >= 1; off >>= 1)
    best = fmaxf(best, __shfl_xor(best, off, 64));
  __shared__ float red[4];
  int wave = threadIdx.x >> 6;
  if ((threadIdx.x & 63) == 0) red[wave] = best;
  __syncthreads();
  if (threadIdx.x == 0) {
    float m = fmaxf(fmaxf(red[0], red[1]), fmaxf(red[2], red[3]));
    kmax2[blockIdx.x] = m;
  }
}

// ---------------- attention via MFMA (flash-style, single pass, C-S bound) --------------
// R7 structure; R8: LDS rows stride 36 u16 (72 B) -> conflict-free P writes (quads land
// on banks {0,8,16,24}); frag loads = 2x ds_read_b64; S uses 3 split-products.
__global__ __launch_bounds__(256, 2) void attn_mfma_kernel(
    const float* __restrict__ qkv, const float* __restrict__ kmax2,
    unsigned short* __restrict__ ohi, unsigned short* __restrict__ olo) {
  int b = blockIdx.x;
  int g = b >> 3;
  int h = (b >> 1) & 3;
  int half = b & 1;
  int t = threadIdx.x;
  int wave = t >> 6;
  int lane = t & 63;
  int quad = lane >> 4;
  int l15 = lane & 15;
  size_t gbase = (size_t)g * NPG;
  int qb = half * 256 + wave * 64;

  const float cf = 0.17677669529663687f * 1.4426950408889634f;  // scale*log2(e)

  __shared__ unsigned short Kh[32][36], Kl[32][36];   // [key][dim], 72 B rows
  __shared__ unsigned short Vh[33][36], Vl[33][36];   // [dim][key]; Vh row 32 = ones
  __shared__ char wbuf[4][9472] __attribute__((aligned(16)));  // per-wave P / O-transpose

  unsigned short* Ph = (unsigned short*)wbuf[wave];        // [64][36] bf16
  unsigned short* Pl = Ph + 64 * 36;                       // [64][36] bf16
  float* Ot = (float*)wbuf[wave];                          // [64][37] f32 (epilogue/qn)

  // ---- Q fragments (scaled by cf, split hi/lo) + |q'|^2 ----
  bf16x8 qh[4], ql[4];
  float qn2p[4];
#pragma unroll
  for (int mt = 0; mt < 4; mt++) {
    const float* qp = &qkv[(gbase + qb + mt * 16 + l15) * 384 + h * 32 + quad * 8];
    float4 f0 = *(const float4*)qp;
    float4 f1 = *(const float4*)(qp + 4);
    float v[8] = {f0.x * cf, f0.y * cf, f0.z * cf, f0.w * cf,
                  f1.x * cf, f1.y * cf, f1.z * cf, f1.w * cf};
    u16x8 hh, ll;
    float s = 0.0f;
#pragma unroll
    for (int j = 0; j < 8; j++) {
      unsigned short hi_, lo_;
      split_bf(v[j], hi_, lo_);
      hh[j] = hi_;
      ll[j] = lo_;
      s = fmaf(v[j], v[j], s);
    }
    qh[mt] = __builtin_bit_cast(bf16x8, hh);
    ql[mt] = __builtin_bit_cast(bf16x8, ll);
    s += __shfl_xor(s, 16);
    s += __shfl_xor(s, 32);
    qn2p[mt] = s;
  }
  if (quad == 0) {
#pragma unroll
    for (int mt = 0; mt < 4; mt++) Ot[mt * 16 + l15] = qn2p[mt];
  }
  float km2 = kmax2[g * 4 + h];
  float Mq[4][4];
#pragma unroll
  for (int mt = 0; mt < 4; mt++)
#pragma unroll
    for (int r = 0; r < 4; r++)
      Mq[mt][r] = sqrtf(Ot[mt * 16 + quad * 4 + r] * km2);

  f32x4 Oa[4][3];
#pragma unroll
  for (int mt = 0; mt < 4; mt++)
#pragma unroll
    for (int nt = 0; nt < 3; nt++) Oa[mt][nt] = (f32x4)0.0f;

  for (int c = 0; c < 16; c++) {
    __syncthreads();
    if (t >= 128) {
      int t2 = t - 128;
      int key = t2 >> 2;
      int ds = (t2 & 3) * 8;
      const float* kp = &qkv[(gbase + (size_t)(c * 32 + key)) * 384 + 128 + h * 32 + ds];
      float4 f0 = *(const float4*)kp;
      float4 f1 = *(const float4*)(kp + 4);
      float v[8] = {f0.x, f0.y, f0.z, f0.w, f1.x, f1.y, f1.z, f1.w};
      u16x4 h0, h1, l0, l1;
#pragma unroll
      for (int j = 0; j < 4; j++) {
        unsigned short hi_, lo_;
        split_bf(v[j], hi_, lo_);
        h0[j] = hi_; l0[j] = lo_;
        split_bf(v[j + 4], hi_, lo_);
        h1[j] = hi_; l1[j] = lo_;
      }
      *(u16x4*)&Kh[key][ds] = h0;
      *(u16x4*)&Kh[key][ds + 4] = h1;
      *(u16x4*)&Kl[key][ds] = l0;
      *(u16x4*)&Kl[key][ds + 4] = l1;
    } else if (t < 64) {
      int keyb = (t & 7) * 4;
      int dvb = (t >> 3) * 4;
      float4 r0 = *(const float4*)&qkv[(gbase + (size_t)(c * 32 + keyb + 0)) * 384 + 256 + h * 32 + dvb];
      float4 r1 = *(const float4*)&qkv[(gbase + (size_t)(c * 32 + keyb + 1)) * 384 + 256 + h * 32 + dvb];
      float4 r2 = *(const float4*)&qkv[(gbase + (size_t)(c * 32 + keyb + 2)) * 384 + 256 + h * 32 + dvb];
      float4 r3 = *(const float4*)&qkv[(gbase + (size_t)(c * 32 + keyb + 3)) * 384 + 256 + h * 32 + dvb];
      float rr[4][4] = {{r0.x, r0.y, r0.z, r0.w}, {r1.x, r1.y, r1.z, r1.w},
                        {r2.x, r2.y, r2.z, r2.w}, {r3.x, r3.y, r3.z, r3.w}};
#pragma unroll
      for (int c2 = 0; c2 < 4; c2++) {
        ushort4 hv, lv;
        unsigned short hi_, lo_;
        split_bf(rr[0][c2], hi_, lo_); hv.x = hi_; lv.x = lo_;
        split_bf(rr[1][c2], hi_, lo_); hv.y = hi_; lv.y = lo_;
        split_bf(rr[2][c2], hi_, lo_); hv.z = hi_; lv.z = lo_;
        split_bf(rr[3][c2], hi_, lo_); hv.w = hi_; lv.w = lo_;
        *(ushort4*)&Vh[dvb + c2][keyb] = hv;
        *(ushort4*)&Vl[dvb + c2][keyb] = lv;
      }
    } else if (t < 68) {
      int i = t - 64;
      u16x8 ones;
#pragma unroll
      for (int j = 0; j < 8; j++) ones[j] = 0x3F80;
      *(u16x4*)&Vh[32][i * 8] = __builtin_shufflevector(ones, ones, 0, 1, 2, 3);
      *(u16x4*)&Vh[32][i * 8 + 4] = __builtin_shufflevector(ones, ones, 4, 5, 6, 7);
    }
    __syncthreads();

    // ---- QK^T -> S -> P ----
#pragma unroll
    for (int nt = 0; nt < 2; nt++) {
      bf16x8 bkh = ld_bf8(&Kh[nt * 16 + l15][quad * 8]);
      bf16x8 bkl = ld_bf8(&Kl[nt * 16 + l15][quad * 8]);
#pragma unroll
      for (int mt = 0; mt < 4; mt++) {
        f32x4 S = (f32x4)0.0f;
        S = __builtin_amdgcn_mfma_f32_16x16x32_bf16(qh[mt], bkh, S, 0, 0, 0);
        S = __builtin_amdgcn_mfma_f32_16x16x32_bf16(qh[mt], bkl, S, 0, 0, 0);
        S = __builtin_amdgcn_mfma_f32_16x16x32_bf16(ql[mt], bkh, S, 0, 0, 0);
#pragma unroll
        for (int r = 0; r < 4; r++) {
          float p = __builtin_exp2f(S[r] - Mq[mt][r]);
          unsigned short hi_, lo_;
          split_bf(p, hi_, lo_);
          int row = mt * 16 + quad * 4 + r;
          Ph[row * 36 + nt * 16 + l15] = hi_;
          Pl[row * 36 + nt * 16 + l15] = lo_;
        }
      }
    }
    // ---- PV ----
    bf16x8 pah[4], pal[4];
#pragma unroll
    for (int mt = 0; mt < 4; mt++) {
      pah[mt] = ld_bf8(&Ph[(mt * 16 + l15) * 36 + quad * 8]);
      pal[mt] = ld_bf8(&Pl[(mt * 16 + l15) * 36 + quad * 8]);
    }
#pragma unroll
    for (int nt = 0; nt < 3; nt++) {
      bf16x8 bvh = ld_bf8(&Vh[nt * 16 + l15][quad * 8]);
      if (nt < 2) {
        bf16x8 bvl = ld_bf8(&Vl[nt * 16 + l15][quad * 8]);
#pragma unroll
        for (int mt = 0; mt < 4; mt++) {
          Oa[mt][nt] = __builtin_amdgcn_mfma_f32_16x16x32_bf16(pah[mt], bvh, Oa[mt][nt], 0, 0, 0);
          Oa[mt][nt] = __builtin_amdgcn_mfma_f32_16x16x32_bf16(pah[mt], bvl, Oa[mt][nt], 0, 0, 0);
          Oa[mt][nt] = __builtin_amdgcn_mfma_f32_16x16x32_bf16(pal[mt], bvh, Oa[mt][nt], 0, 0, 0);
        }
      } else {
#pragma unroll
        for (int mt = 0; mt < 4; mt++) {
          Oa[mt][nt] = __builtin_amdgcn_mfma_f32_16x16x32_bf16(pah[mt], bvh, Oa[mt][nt], 0, 0, 0);
          Oa[mt][nt] = __builtin_amdgcn_mfma_f32_16x16x32_bf16(pal[mt], bvh, Oa[mt][nt], 0, 0, 0);
        }
      }
    }
  }

  // ---- epilogue: transpose O through per-wave LDS (stride 37), normalize, store ----
#pragma unroll
  for (int mt = 0; mt < 4; mt++) {
#pragma unroll
    for (int r = 0; r < 4; r++) {
      int row = mt * 16 + quad * 4 + r;
      Ot[row * 37 + l15] = Oa[mt][0][r];
      Ot[row * 37 + 16 + l15] = Oa[mt][1][r];
      if (l15 == 0) Ot[row * 37 + 32] = Oa[mt][2][r];
    }
  }
  {
    int row = lane;
    float inv = 1.0f / Ot[row * 37 + 32];
    size_t node = gbase + qb + row;
    u16x8 vh, vl;
#pragma unroll
    for (int seg = 0; seg < 4; seg++) {
#pragma unroll
      for (int j = 0; j < 8; j++) {
        unsigned short hi_, lo_;
        split_bf(Ot[row * 37 + seg * 8 + j] * inv, hi_, lo_);
        vh[j] = hi_;
        vl[j] = lo_;
      }
      *(u16x8*)(ohi + node * 128 + h * 32 + seg * 8) = vh;
      *(u16x8*)(olo + node * 128 + h * 32 + seg * 8) = vl;
    }
  }
}

// ---------------- mean pool ----------------
__global__ __launch_bounds__(128) void pool_kernel(const float* __restrict__ fin,
                                                   float* __restrict__ emb) {
  int g = blockIdx.x, c = threadIdx.x;
  const float* p = fin + (size_t)g * NPG * HID + c;
  float s = 0.0f;
  for (int i = 0; i < NPG; i++) s += p[(size_t)i * HID];
  emb[g * HID + c] = s * (1.0f / NPG);
}

extern "C" void kernel_launch(void* const* d_in, const int* in_sizes, int n_in,
                              void* d_out, int out_size, void* d_ws, size_t ws_size,
                              hipStream_t stream) {
  (void)in_sizes; (void)n_in; (void)out_size; (void)ws_size;
  const float* x          = (const float*)d_in[0];
  const float* W0         = (const float*)d_in[1];
  const float* b0         = (const float*)d_in[2];
  const float* Wh         = (const float*)d_in[3];
  const float* bh         = (const float*)d_in[4];
  const float* bn_gamma   = (const float*)d_in[5];
  const float* bn_beta    = (const float*)d_in[6];
  const float* bn_mean    = (const float*)d_in[7];
  const float* bn_var     = (const float*)d_in[8];
  const float* attn_in_w  = (const float*)d_in[9];
  const float* attn_in_b  = (const float*)d_in[10];
  const float* attn_out_w = (const float*)d_in[11];
  const float* attn_out_b = (const float*)d_in[12];
  const int* edge_index   = (const int*)d_in[13];
  const int* src = edge_index;
  const int* dst = edge_index + N_EDGES;

  char* ws = (char*)d_ws;
  size_t off = 0;
  auto alloc = [&](size_t bytes) -> void* {
    void* p = ws + off;
    off += (bytes + 255) & ~(size_t)255;
    return p;
  };
  int*   deg     = (int*)alloc((size_t)N_NODES * 4);
  int*   offsets = (int*)alloc((size_t)(N_NODES + 1) * 4);
  int*   cursor  = (int*)alloc((size_t)N_NODES * 4);
  int*   csr     = (int*)alloc((size_t)N_EDGES * 4);
  float* dis     = (float*)alloc((size_t)N_NODES * 4);
  float* bufA    = (float*)alloc((size_t)N_NODES * HID * 4);   // h fp32; later f_hi/f_lo
  unsigned short* zhi = (unsigned short*)alloc((size_t)N_NODES * HID * 2);  // also o_hi
  unsigned short* zlo = (unsigned short*)alloc((size_t)N_NODES * HID * 2);  // also o_lo
  float* qkvb    = (float*)alloc((size_t)N_NODES * 384 * 4);
  float* kmax2   = (float*)alloc((size_t)N_GRAPHS * 4 * 4);
  unsigned short* w0h = (unsigned short*)alloc(8192 * 2);
  unsigned short* w0l = (unsigned short*)alloc(8192 * 2);
  unsigned short* whh[3], *whl[3];
  for (int i = 0; i < 3; i++) {
    whh[i] = (unsigned short*)alloc(16384 * 2);
    whl[i] = (unsigned short*)alloc(16384 * 2);
  }
  unsigned short* wqh = (unsigned short*)alloc(49152 * 2);
  unsigned short* wql = (unsigned short*)alloc(49152 * 2);
  unsigned short* woh = (unsigned short*)alloc(16384 * 2);
  unsigned short* wol = (unsigned short*)alloc(16384 * 2);

  unsigned short* fhi = (unsigned short*)bufA;
  unsigned short* flo = fhi + (size_t)N_NODES * HID;

  float* fin = (float*)d_out;                       // [N, HID]
  float* emb = fin + (size_t)N_NODES * HID;         // [G, HID]

  hipMemsetAsync(deg, 0, (size_t)N_NODES * 4, stream);
  hist_kernel<<<N_EDGES / 256, 256, 0, stream>>>(dst, deg);
  dis_kernel<<<N_NODES / 256, 256, 0, stream>>>(deg, dis);
  scan_kernel<<<1, 1024, 0, stream>>>(deg, offsets, cursor);
  fill_kernel<<<N_EDGES / 256, 256, 0, stream>>>(src, dst, cursor, csr);

  wprep_kernel<false><<<4, 256, 0, stream>>>(W0, 64, 128, w0h, w0l);
  for (int i = 0; i < 3; i++)
    wprep_kernel<false><<<8, 256, 0, stream>>>(Wh + (size_t)i * HID * HID, 128, 128,
                                               whh[i], whl[i]);
  wprep_kernel<true><<<24, 256, 0, stream>>>(attn_in_w, 128, 384, wqh, wql);
  wprep_kernel<true><<<8, 256, 0, stream>>>(attn_out_w, 128, 128, woh, wol);

  dim3 ggrid(N_NODES / 128, 1);
  agg64_kernel<<<N_NODES, 256, 0, stream>>>(x, dis, offsets, csr, zhi, zlo);
  gemm_mfma<64, 128, true, true, false><<<ggrid, 256, 0, stream>>>(
      zhi, zlo, w0h, w0l, b0, bn_gamma, bn_beta, bn_mean, bn_var, bufA, nullptr, nullptr);
  for (int L = 0; L < 2; L++) {
    agg128_kernel<<<N_NODES, 256, 0, stream>>>(bufA, dis, offsets, csr, zhi, zlo);
    gemm_mfma<128, 128, true, true, false><<<ggrid, 256, 0, stream>>>(
        zhi, zlo, whh[L], whl[L], bh + (size_t)L * HID,
        bn_gamma + (size_t)(L + 1) * HID, bn_beta + (size_t)(L + 1) * HID,
        bn_mean + (size_t)(L + 1) * HID, bn_var + (size_t)(L + 1) * HID,
        bufA, nullptr, nullptr);
  }
  agg128_kernel<<<N_NODES, 256, 0, stream>>>(bufA, dis, offsets, csr, zhi, zlo);
  gemm_mfma<128, 128, true, true, true><<<ggrid, 256, 0, stream>>>(
      zhi, zlo, whh[2], whl[2], bh + (size_t)2 * HID,
      bn_gamma + (size_t)3 * HID, bn_beta + (size_t)3 * HID,
      bn_mean + (size_t)3 * HID, bn_var + (size_t)3 * HID,
      nullptr, fhi, flo);
  dim3 qgrid(N_NODES / 128, 3);
  gemm_mfma<128, 384, false, false, false><<<qgrid, 256, 0, stream>>>(
      fhi, flo, wqh, wql, attn_in_b, nullptr, nullptr, nullptr, nullptr,
      qkvb, nullptr, nullptr);
  knorm_kernel<<<N_GRAPHS * 4, 256, 0, stream>>>(qkvb, kmax2);
  attn_mfma_kernel<<<N_GRAPHS * 4 * 2, 256, 0, stream>>>(qkvb, kmax2, zhi, zlo);
  gemm_mfma<128, 128, false, false, false><<<ggrid, 256, 0, stream>>>(
      zhi, zlo, woh, wol, attn_out_b, nullptr, nullptr, nullptr, nullptr,
      fin, nullptr, nullptr);
  pool_kernel<<<N_GRAPHS, 128, 0, stream>>>(fin, emb);
}

// Round 9
// 841.868 us; speedup vs baseline: 1.0748x; 1.0748x over previous
//
#include <hip/hip_runtime.h>
#include <hip/hip_bf16.h>
#include <cstdint>
#include <cstddef>

#define N_NODES 65536
#define N_EDGES 1048576
#define N_GRAPHS 128
#define NPG 512
#define IN_DIM 64
#define HID 128
#define BN_EPS 1e-5f

typedef __attribute__((ext_vector_type(8))) short bf16x8;
typedef __attribute__((ext_vector_type(4))) float f32x4;
typedef __attribute__((ext_vector_type(8))) unsigned short u16x8;
typedef __attribute__((ext_vector_type(4))) unsigned short u16x4;

// ---- bf16 helpers (RNE, matches v_cvt) ----
__device__ inline unsigned short f2bf(float f) {
  unsigned u = __builtin_bit_cast(unsigned, f);
  u = u + 0x7fffu + ((u >> 16) & 1u);
  return (unsigned short)(u >> 16);
}
__device__ inline float bf2f(unsigned short h) {
  unsigned u = ((unsigned)h) << 16;
  return __builtin_bit_cast(float, u);
}
__device__ inline void split_bf(float v, unsigned short& hi, unsigned short& lo) {
  hi = f2bf(v);
  lo = f2bf(v - bf2f(hi));
}
// 8-B-aligned LDS fragment load (two ds_read_b64) — rows stride 36 u16 = 72 B
__device__ inline bf16x8 ld_bf8(const unsigned short* p) {
  u16x4 a = *(const u16x4*)p;
  u16x4 b = *(const u16x4*)(p + 4);
  u16x8 r = __builtin_shufflevector(a, b, 0, 1, 2, 3, 4, 5, 6, 7);
  return __builtin_bit_cast(bf16x8, r);
}

// ---------------- CSR build ----------------
__global__ __launch_bounds__(256) void hist_kernel(const int* __restrict__ dst,
                                                   int* __restrict__ deg) {
  int e = blockIdx.x * 256 + threadIdx.x;
  if (e < N_EDGES) atomicAdd(&deg[dst[e]], 1);
}

__global__ __launch_bounds__(256) void dis_kernel(const int* __restrict__ deg,
                                                  float* __restrict__ dis) {
  int n = blockIdx.x * 256 + threadIdx.x;
  if (n < N_NODES) dis[n] = 1.0f / sqrtf((float)deg[n] + 1.0f);
}

__global__ __launch_bounds__(1024) void scan_kernel(const int* __restrict__ deg,
                                                    int* __restrict__ offsets,
                                                    int* __restrict__ cursor) {
  __shared__ int sums[1024];
  int t = threadIdx.x;
  int base = t * 64;
  const int4* dp = (const int4*)(deg + base);
  int s = 0;
#pragma unroll
  for (int i = 0; i < 16; i++) {
    int4 v = dp[i];
    s += v.x + v.y + v.z + v.w;
  }
  sums[t] = s;
  __syncthreads();
  for (int off = 1; off < 1024; off <<= 1) {
    int v = (t >= off) ? sums[t - off] : 0;
    __syncthreads();
    sums[t] += v;
    __syncthreads();
  }
  int run = (t == 0) ? 0 : sums[t - 1];
#pragma unroll
  for (int i = 0; i < 16; i++) {
    int4 v = dp[i];
    int idx = base + i * 4;
    offsets[idx] = run; cursor[idx] = run; run += v.x;
    offsets[idx + 1] = run; cursor[idx + 1] = run; run += v.y;
    offsets[idx + 2] = run; cursor[idx + 2] = run; run += v.z;
    offsets[idx + 3] = run; cursor[idx + 3] = run; run += v.w;
  }
  if (t == 1023) offsets[N_NODES] = run;
}

// fill also precomputes per-edge GCN weight: wedge = dis[src]*dis[dst]
// (removes the dependent dis[s] gather from all 4 aggregation loops)
__global__ __launch_bounds__(256) void fill_kernel(const int* __restrict__ src,
                                                   const int* __restrict__ dst,
                                                   const float* __restrict__ dis,
                                                   int* __restrict__ cursor,
                                                   int* __restrict__ csr,
                                                   float* __restrict__ wedge) {
  int e = blockIdx.x * 256 + threadIdx.x;
  if (e < N_EDGES) {
    int d = dst[e];
    int s = src[e];
    int slot = atomicAdd(&cursor[d], 1);
    csr[slot] = s;
    wedge[slot] = dis[s] * dis[d];
  }
}

// ---------------- aggregation: wave-per-node (R6 shape), chunk-8 ILP, wedge weights ----
__global__ __launch_bounds__(256) void agg64_kernel(const float* __restrict__ x,
                                                    const float* __restrict__ dis,
                                                    const float* __restrict__ wedge,
                                                    const int* __restrict__ offsets,
                                                    const int* __restrict__ csr,
                                                    unsigned short* __restrict__ zhi,
                                                    unsigned short* __restrict__ zlo) {
  int node = blockIdx.x * 4 + (threadIdx.x >> 6);
  int lane = threadIdx.x & 63;
  float dn = dis[node];
  float acc = x[(size_t)node * 64 + lane] * dn * dn;
  int beg = offsets[node], end = offsets[node + 1];
  int k = beg;
  for (; k + 8 <= end; k += 8) {
    int s[8];
    float w[8], v[8];
#pragma unroll
    for (int i = 0; i < 8; i++) {
      s[i] = csr[k + i];
      w[i] = wedge[k + i];
    }
#pragma unroll
    for (int i = 0; i < 8; i++) v[i] = x[(size_t)s[i] * 64 + lane];
#pragma unroll
    for (int i = 0; i < 8; i++) acc = fmaf(w[i], v[i], acc);
  }
  for (; k + 4 <= end; k += 4) {
    int s0 = csr[k], s1 = csr[k + 1], s2 = csr[k + 2], s3 = csr[k + 3];
    float w0 = wedge[k], w1 = wedge[k + 1], w2 = wedge[k + 2], w3 = wedge[k + 3];
    float v0 = x[(size_t)s0 * 64 + lane];
    float v1 = x[(size_t)s1 * 64 + lane];
    float v2 = x[(size_t)s2 * 64 + lane];
    float v3 = x[(size_t)s3 * 64 + lane];
    acc = fmaf(w0, v0, acc);
    acc = fmaf(w1, v1, acc);
    acc = fmaf(w2, v2, acc);
    acc = fmaf(w3, v3, acc);
  }
  for (; k < end; k++) {
    int s = csr[k];
    acc = fmaf(wedge[k], x[(size_t)s * 64 + lane], acc);
  }
  unsigned short h_, l_;
  split_bf(acc, h_, l_);
  zhi[(size_t)node * 64 + lane] = h_;
  zlo[(size_t)node * 64 + lane] = l_;
}

__global__ __launch_bounds__(256) void agg128_kernel(const float* __restrict__ h,
                                                     const float* __restrict__ dis,
                                                     const float* __restrict__ wedge,
                                                     const int* __restrict__ offsets,
                                                     const int* __restrict__ csr,
                                                     unsigned short* __restrict__ zhi,
                                                     unsigned short* __restrict__ zlo) {
  int node = blockIdx.x * 4 + (threadIdx.x >> 6);
  int lane = threadIdx.x & 63;
  float dn = dis[node];
  float sn = dn * dn;
  const float* hr = h + (size_t)node * 128;
  float a0 = hr[lane] * sn;
  float a1 = hr[lane + 64] * sn;
  int beg = offsets[node], end = offsets[node + 1];
  int k = beg;
  for (; k + 8 <= end; k += 8) {
    int s[8];
    float w[8], u[8], d[8];
#pragma unroll
    for (int i = 0; i < 8; i++) {
      s[i] = csr[k + i];
      w[i] = wedge[k + i];
    }
#pragma unroll
    for (int i = 0; i < 8; i++) {
      const float* p = h + (size_t)s[i] * 128;
      u[i] = p[lane];
      d[i] = p[lane + 64];
    }
#pragma unroll
    for (int i = 0; i < 8; i++) {
      a0 = fmaf(w[i], u[i], a0);
      a1 = fmaf(w[i], d[i], a1);
    }
  }
  for (; k + 4 <= end; k += 4) {
    int s0 = csr[k], s1 = csr[k + 1], s2 = csr[k + 2], s3 = csr[k + 3];
    float w0 = wedge[k], w1 = wedge[k + 1], w2 = wedge[k + 2], w3 = wedge[k + 3];
    const float* p0 = h + (size_t)s0 * 128;
    const float* p1 = h + (size_t)s1 * 128;
    const float* p2 = h + (size_t)s2 * 128;
    const float* p3 = h + (size_t)s3 * 128;
    float u0 = p0[lane], d0 = p0[lane + 64];
    float u1 = p1[lane], d1 = p1[lane + 64];
    float u2 = p2[lane], d2 = p2[lane + 64];
    float u3 = p3[lane], d3 = p3[lane + 64];
    a0 = fmaf(w0, u0, a0); a1 = fmaf(w0, d0, a1);
    a0 = fmaf(w1, u1, a0); a1 = fmaf(w1, d1, a1);
    a0 = fmaf(w2, u2, a0); a1 = fmaf(w2, d2, a1);
    a0 = fmaf(w3, u3, a0); a1 = fmaf(w3, d3, a1);
  }
  for (; k < end; k++) {
    int s = csr[k];
    float wt = wedge[k];
    const float* hs = h + (size_t)s * 128;
    a0 = fmaf(wt, hs[lane], a0);
    a1 = fmaf(wt, hs[lane + 64], a1);
  }
  unsigned short h0, l0, h1, l1;
  split_bf(a0, h0, l0);
  split_bf(a1, h1, l1);
  zhi[(size_t)node * 128 + lane] = h0;
  zlo[(size_t)node * 128 + lane] = l0;
  zhi[(size_t)node * 128 + lane + 64] = h1;
  zlo[(size_t)node * 128 + lane + 64] = l1;
}

// ---------------- weight prep: fp32 W -> bf16 hi/lo in b-fragment layout ----------------
template <bool TRANS>
__global__ __launch_bounds__(256) void wprep_kernel(const float* __restrict__ W, int K, int O,
                                                    unsigned short* __restrict__ hi,
                                                    unsigned short* __restrict__ lo) {
  int idx = blockIdx.x * 256 + threadIdx.x;
  int KC = K / 32;
  int total = (O / 16) * KC * 64;
  if (idx >= total) return;
  int lane = idx & 63;
  int rest = idx >> 6;
  int kc = rest % KC;
  int nt = rest / KC;
  int n = nt * 16 + (lane & 15);
  int kb = kc * 32 + (lane >> 4) * 8;
  unsigned short* hp = hi + (size_t)idx * 8;
  unsigned short* lp = lo + (size_t)idx * 8;
#pragma unroll
  for (int j = 0; j < 8; j++) {
    int k = kb + j;
    float v = TRANS ? W[(size_t)n * K + k] : W[(size_t)k * O + n];
    unsigned short h_, l_;
    split_bf(v, h_, l_);
    hp[j] = h_;
    lp[j] = l_;
  }
}

// ---------------- MFMA GEMM (3 split-products: hh + hl + lh) ----------------
template <int K, int O, bool DOBN, bool DORELU, bool SPLIT_OUT>
__global__ __launch_bounds__(256) void gemm_mfma(
    const unsigned short* __restrict__ Ahi, const unsigned short* __restrict__ Alo,
    const unsigned short* __restrict__ Whi, const unsigned short* __restrict__ Wlo,
    const float* __restrict__ bias,
    const float* __restrict__ gamma, const float* __restrict__ beta,
    const float* __restrict__ mean, const float* __restrict__ var,
    float* __restrict__ Cf, unsigned short* __restrict__ Chi,
    unsigned short* __restrict__ Clo) {
  constexpr int KC = K / 32;
  int wave = threadIdx.x >> 6;
  int lane = threadIdx.x & 63;
  int m0 = blockIdx.x * 128 + wave * 32;
  int o0 = blockIdx.y * 128;
  int mrow = lane & 15;
  int kseg = (lane >> 4) * 8;

  f32x4 acc[2][8];
#pragma unroll
  for (int mt = 0; mt < 2; mt++)
#pragma unroll
    for (int nt = 0; nt < 8; nt++) acc[mt][nt] = (f32x4)0.0f;

#pragma unroll
  for (int kc = 0; kc < KC; kc++) {
    bf16x8 ah[2], al[2];
#pragma unroll
    for (int mt = 0; mt < 2; mt++) {
      size_t aoff = (size_t)(m0 + mt * 16 + mrow) * K + kc * 32 + kseg;
      ah[mt] = *(const bf16x8*)(Ahi + aoff);
      al[mt] = *(const bf16x8*)(Alo + aoff);
    }
#pragma unroll
    for (int nt = 0; nt < 8; nt++) {
      size_t foff = (((size_t)(blockIdx.y * 8 + nt) * KC + kc) * 64 + lane) * 8;
      bf16x8 bh = *(const bf16x8*)(Whi + foff);
      bf16x8 bl = *(const bf16x8*)(Wlo + foff);
#pragma unroll
      for (int mt = 0; mt < 2; mt++) {
        acc[mt][nt] = __builtin_amdgcn_mfma_f32_16x16x32_bf16(ah[mt], bh, acc[mt][nt], 0, 0, 0);
        acc[mt][nt] = __builtin_amdgcn_mfma_f32_16x16x32_bf16(ah[mt], bl, acc[mt][nt], 0, 0, 0);
        acc[mt][nt] = __builtin_amdgcn_mfma_f32_16x16x32_bf16(al[mt], bh, acc[mt][nt], 0, 0, 0);
      }
    }
  }

  int ccol = lane & 15;
  int crow0 = (lane >> 4) * 4;
#pragma unroll
  for (int nt = 0; nt < 8; nt++) {
    int c = o0 + nt * 16 + ccol;
    float sc, cb;
    float b = bias[c];
    if (DOBN) {
      sc = gamma[c] * rsqrtf(var[c] + BN_EPS);
      cb = (b - mean[c]) * sc + beta[c];
    } else {
      sc = 1.0f;
      cb = b;
    }
#pragma unroll
    for (int mt = 0; mt < 2; mt++) {
#pragma unroll
      for (int r = 0; r < 4; r++) {
        float v = fmaf(acc[mt][nt][r], sc, cb);
        if (DORELU) v = fmaxf(v, 0.0f);
        size_t row = (size_t)(m0 + mt * 16 + crow0 + r);
        if (SPLIT_OUT) {
          unsigned short h_, l_;
          split_bf(v, h_, l_);
          Chi[row * O + c] = h_;
          Clo[row * O + c] = l_;
        } else {
          Cf[row * O + c] = v;
        }
      }
    }
  }
}

// ---------------- key-norm max per (graph, head) ----------------
__global__ __launch_bounds__(256) void knorm_kernel(const float* __restrict__ qkv,
                                                    float* __restrict__ kmax2) {
  int g = blockIdx.x >> 2;
  int h = blockIdx.x & 3;
  size_t gbase = (size_t)g * NPG;
  float best = 0.0f;
#pragma unroll
  for (int r = 0; r < 2; r++) {
    int j = r * 256 + threadIdx.x;
    const float* kp = &qkv[(gbase + j) * 384 + 128 + h * 32];
    float s = 0.0f;
#pragma unroll
    for (int i = 0; i < 8; i++) {
      float4 v = *(const float4*)(kp + i * 4);
      s = fmaf(v.x, v.x, s);
      s = fmaf(v.y, v.y, s);
      s = fmaf(v.z, v.z, s);
      s = fmaf(v.w, v.w, s);
    }
    best = fmaxf(best, s);
  }
#pragma unroll
  for (int off = 32; off >= 1; off >>= 1)
    best = fmaxf(best, __shfl_xor(best, off, 64));
  __shared__ float red[4];
  int wave = threadIdx.x >> 6;
  if ((threadIdx.x & 63) == 0) red[wave] = best;
  __syncthreads();
  if (threadIdx.x == 0) {
    float m = fmaxf(fmaxf(red[0], red[1]), fmaxf(red[2], red[3]));
    kmax2[blockIdx.x] = m;
  }
}

// ---------------- attention via MFMA (R8 version, kept) ----------------
__global__ __launch_bounds__(256, 2) void attn_mfma_kernel(
    const float* __restrict__ qkv, const float* __restrict__ kmax2,
    unsigned short* __restrict__ ohi, unsigned short* __restrict__ olo) {
  int b = blockIdx.x;
  int g = b >> 3;
  int h = (b >> 1) & 3;
  int half = b & 1;
  int t = threadIdx.x;
  int wave = t >> 6;
  int lane = t & 63;
  int quad = lane >> 4;
  int l15 = lane & 15;
  size_t gbase = (size_t)g * NPG;
  int qb = half * 256 + wave * 64;

  const float cf = 0.17677669529663687f * 1.4426950408889634f;  // scale*log2(e)

  __shared__ unsigned short Kh[32][36], Kl[32][36];
  __shared__ unsigned short Vh[33][36], Vl[33][36];
  __shared__ char wbuf[4][9472] __attribute__((aligned(16)));

  unsigned short* Ph = (unsigned short*)wbuf[wave];
  unsigned short* Pl = Ph + 64 * 36;
  float* Ot = (float*)wbuf[wave];

  bf16x8 qh[4], ql[4];
  float qn2p[4];
#pragma unroll
  for (int mt = 0; mt < 4; mt++) {
    const float* qp = &qkv[(gbase + qb + mt * 16 + l15) * 384 + h * 32 + quad * 8];
    float4 f0 = *(const float4*)qp;
    float4 f1 = *(const float4*)(qp + 4);
    float v[8] = {f0.x * cf, f0.y * cf, f0.z * cf, f0.w * cf,
                  f1.x * cf, f1.y * cf, f1.z * cf, f1.w * cf};
    u16x8 hh, ll;
    float s = 0.0f;
#pragma unroll
    for (int j = 0; j < 8; j++) {
      unsigned short hi_, lo_;
      split_bf(v[j], hi_, lo_);
      hh[j] = hi_;
      ll[j] = lo_;
      s = fmaf(v[j], v[j], s);
    }
    qh[mt] = __builtin_bit_cast(bf16x8, hh);
    ql[mt] = __builtin_bit_cast(bf16x8, ll);
    s += __shfl_xor(s, 16);
    s += __shfl_xor(s, 32);
    qn2p[mt] = s;
  }
  if (quad == 0) {
#pragma unroll
    for (int mt = 0; mt < 4; mt++) Ot[mt * 16 + l15] = qn2p[mt];
  }
  float km2 = kmax2[g * 4 + h];
  float Mq[4][4];
#pragma unroll
  for (int mt = 0; mt < 4; mt++)
#pragma unroll
    for (int r = 0; r < 4; r++)
      Mq[mt][r] = sqrtf(Ot[mt * 16 + quad * 4 + r] * km2);

  f32x4 Oa[4][3];
#pragma unroll
  for (int mt = 0; mt < 4; mt++)
#pragma unroll
    for (int nt = 0; nt < 3; nt++) Oa[mt][nt] = (f32x4)0.0f;

  for (int c = 0; c < 16; c++) {
    __syncthreads();
    if (t >= 128) {
      int t2 = t - 128;
      int key = t2 >> 2;
      int ds = (t2 & 3) * 8;
      const float* kp = &qkv[(gbase + (size_t)(c * 32 + key)) * 384 + 128 + h * 32 + ds];
      float4 f0 = *(const float4*)kp;
      float4 f1 = *(const float4*)(kp + 4);
      float v[8] = {f0.x, f0.y, f0.z, f0.w, f1.x, f1.y, f1.z, f1.w};
      u16x4 h0, h1, l0, l1;
#pragma unroll
      for (int j = 0; j < 4; j++) {
        unsigned short hi_, lo_;
        split_bf(v[j], hi_, lo_);
        h0[j] = hi_; l0[j] = lo_;
        split_bf(v[j + 4], hi_, lo_);
        h1[j] = hi_; l1[j] = lo_;
      }
      *(u16x4*)&Kh[key][ds] = h0;
      *(u16x4*)&Kh[key][ds + 4] = h1;
      *(u16x4*)&Kl[key][ds] = l0;
      *(u16x4*)&Kl[key][ds + 4] = l1;
    } else if (t < 64) {
      int keyb = (t & 7) * 4;
      int dvb = (t >> 3) * 4;
      float4 r0 = *(const float4*)&qkv[(gbase + (size_t)(c * 32 + keyb + 0)) * 384 + 256 + h * 32 + dvb];
      float4 r1 = *(const float4*)&qkv[(gbase + (size_t)(c * 32 + keyb + 1)) * 384 + 256 + h * 32 + dvb];
      float4 r2 = *(const float4*)&qkv[(gbase + (size_t)(c * 32 + keyb + 2)) * 384 + 256 + h * 32 + dvb];
      float4 r3 = *(const float4*)&qkv[(gbase + (size_t)(c * 32 + keyb + 3)) * 384 + 256 + h * 32 + dvb];
      float rr[4][4] = {{r0.x, r0.y, r0.z, r0.w}, {r1.x, r1.y, r1.z, r1.w},
                        {r2.x, r2.y, r2.z, r2.w}, {r3.x, r3.y, r3.z, r3.w}};
#pragma unroll
      for (int c2 = 0; c2 < 4; c2++) {
        ushort4 hv, lv;
        unsigned short hi_, lo_;
        split_bf(rr[0][c2], hi_, lo_); hv.x = hi_; lv.x = lo_;
        split_bf(rr[1][c2], hi_, lo_); hv.y = hi_; lv.y = lo_;
        split_bf(rr[2][c2], hi_, lo_); hv.z = hi_; lv.z = lo_;
        split_bf(rr[3][c2], hi_, lo_); hv.w = hi_; lv.w = lo_;
        *(ushort4*)&Vh[dvb + c2][keyb] = hv;
        *(ushort4*)&Vl[dvb + c2][keyb] = lv;
      }
    } else if (t < 68) {
      int i = t - 64;
      u16x8 ones;
#pragma unroll
      for (int j = 0; j < 8; j++) ones[j] = 0x3F80;
      *(u16x4*)&Vh[32][i * 8] = __builtin_shufflevector(ones, ones, 0, 1, 2, 3);
      *(u16x4*)&Vh[32][i * 8 + 4] = __builtin_shufflevector(ones, ones, 4, 5, 6, 7);
    }
    __syncthreads();

#pragma unroll
    for (int nt = 0; nt < 2; nt++) {
      bf16x8 bkh = ld_bf8(&Kh[nt * 16 + l15][quad * 8]);
      bf16x8 bkl = ld_bf8(&Kl[nt * 16 + l15][quad * 8]);
#pragma unroll
      for (int mt = 0; mt < 4; mt++) {
        f32x4 S = (f32x4)0.0f;
        S = __builtin_amdgcn_mfma_f32_16x16x32_bf16(qh[mt], bkh, S, 0, 0, 0);
        S = __builtin_amdgcn_mfma_f32_16x16x32_bf16(qh[mt], bkl, S, 0, 0, 0);
        S = __builtin_amdgcn_mfma_f32_16x16x32_bf16(ql[mt], bkh, S, 0, 0, 0);
#pragma unroll
        for (int r = 0; r < 4; r++) {
          float p = __builtin_exp2f(S[r] - Mq[mt][r]);
          unsigned short hi_, lo_;
          split_bf(p, hi_, lo_);
          int row = mt * 16 + quad * 4 + r;
          Ph[row * 36 + nt * 16 + l15] = hi_;
          Pl[row * 36 + nt * 16 + l15] = lo_;
        }
      }
    }
    bf16x8 pah[4], pal[4];
#pragma unroll
    for (int mt = 0; mt < 4; mt++) {
      pah[mt] = ld_bf8(&Ph[(mt * 16 + l15) * 36 + quad * 8]);
      pal[mt] = ld_bf8(&Pl[(mt * 16 + l15) * 36 + quad * 8]);
    }
#pragma unroll
    for (int nt = 0; nt < 3; nt++) {
      bf16x8 bvh = ld_bf8(&Vh[nt * 16 + l15][quad * 8]);
      if (nt < 2) {
        bf16x8 bvl = ld_bf8(&Vl[nt * 16 + l15][quad * 8]);
#pragma unroll
        for (int mt = 0; mt < 4; mt++) {
          Oa[mt][nt] = __builtin_amdgcn_mfma_f32_16x16x32_bf16(pah[mt], bvh, Oa[mt][nt], 0, 0, 0);
          Oa[mt][nt] = __builtin_amdgcn_mfma_f32_16x16x32_bf16(pah[mt], bvl, Oa[mt][nt], 0, 0, 0);
          Oa[mt][nt] = __builtin_amdgcn_mfma_f32_16x16x32_bf16(pal[mt], bvh, Oa[mt][nt], 0, 0, 0);
        }
      } else {
#pragma unroll
        for (int mt = 0; mt < 4; mt++) {
          Oa[mt][nt] = __builtin_amdgcn_mfma_f32_16x16x32_bf16(pah[mt], bvh, Oa[mt][nt], 0, 0, 0);
          Oa[mt][nt] = __builtin_amdgcn_mfma_f32_16x16x32_bf16(pal[mt], bvh, Oa[mt][nt], 0, 0, 0);
        }
      }
    }
  }

#pragma unroll
  for (int mt = 0; mt < 4; mt++) {
#pragma unroll
    for (int r = 0; r < 4; r++) {
      int row = mt * 16 + quad * 4 + r;
      Ot[row * 37 + l15] = Oa[mt][0][r];
      Ot[row * 37 + 16 + l15] = Oa[mt][1][r];
      if (l15 == 0) Ot[row * 37 + 32] = Oa[mt][2][r];
    }
  }
  {
    int row = lane;
    float inv = 1.0f / Ot[row * 37 + 32];
    size_t node = gbase + qb + row;
    u16x8 vh, vl;
#pragma unroll
    for (int seg = 0; seg < 4; seg++) {
#pragma unroll
      for (int j = 0; j < 8; j++) {
        unsigned short hi_, lo_;
        split_bf(Ot[row * 37 + seg * 8 + j] * inv, hi_, lo_);
        vh[j] = hi_;
        vl[j] = lo_;
      }
      *(u16x8*)(ohi + node * 128 + h * 32 + seg * 8) = vh;
      *(u16x8*)(olo + node * 128 + h * 32 + seg * 8) = vl;
    }
  }
}

// ---------------- mean pool ----------------
__global__ __launch_bounds__(128) void pool_kernel(const float* __restrict__ fin,
                                                   float* __restrict__ emb) {
  int g = blockIdx.x, c = threadIdx.x;
  const float* p = fin + (size_t)g * NPG * HID + c;
  float s = 0.0f;
  for (int i = 0; i < NPG; i++) s += p[(size_t)i * HID];
  emb[g * HID + c] = s * (1.0f / NPG);
}

extern "C" void kernel_launch(void* const* d_in, const int* in_sizes, int n_in,
                              void* d_out, int out_size, void* d_ws, size_t ws_size,
                              hipStream_t stream) {
  (void)in_sizes; (void)n_in; (void)out_size; (void)ws_size;
  const float* x          = (const float*)d_in[0];
  const float* W0         = (const float*)d_in[1];
  const float* b0         = (const float*)d_in[2];
  const float* Wh         = (const float*)d_in[3];
  const float* bh         = (const float*)d_in[4];
  const float* bn_gamma   = (const float*)d_in[5];
  const float* bn_beta    = (const float*)d_in[6];
  const float* bn_mean    = (const float*)d_in[7];
  const float* bn_var     = (const float*)d_in[8];
  const float* attn_in_w  = (const float*)d_in[9];
  const float* attn_in_b  = (const float*)d_in[10];
  const float* attn_out_w = (const float*)d_in[11];
  const float* attn_out_b = (const float*)d_in[12];
  const int* edge_index   = (const int*)d_in[13];
  const int* src = edge_index;
  const int* dst = edge_index + N_EDGES;

  char* ws = (char*)d_ws;
  size_t off = 0;
  auto alloc = [&](size_t bytes) -> void* {
    void* p = ws + off;
    off += (bytes + 255) & ~(size_t)255;
    return p;
  };
  int*   deg     = (int*)alloc((size_t)N_NODES * 4);
  int*   offsets = (int*)alloc((size_t)(N_NODES + 1) * 4);
  int*   cursor  = (int*)alloc((size_t)N_NODES * 4);
  int*   csr     = (int*)alloc((size_t)N_EDGES * 4);
  float* wedge   = (float*)alloc((size_t)N_EDGES * 4);
  float* dis     = (float*)alloc((size_t)N_NODES * 4);
  float* bufA    = (float*)alloc((size_t)N_NODES * HID * 4);   // h fp32; later f_hi/f_lo
  unsigned short* zhi = (unsigned short*)alloc((size_t)N_NODES * HID * 2);  // also o_hi
  unsigned short* zlo = (unsigned short*)alloc((size_t)N_NODES * HID * 2);  // also o_lo
  float* qkvb    = (float*)alloc((size_t)N_NODES * 384 * 4);
  float* kmax2   = (float*)alloc((size_t)N_GRAPHS * 4 * 4);
  unsigned short* w0h = (unsigned short*)alloc(8192 * 2);
  unsigned short* w0l = (unsigned short*)alloc(8192 * 2);
  unsigned short* whh[3], *whl[3];
  for (int i = 0; i < 3; i++) {
    whh[i] = (unsigned short*)alloc(16384 * 2);
    whl[i] = (unsigned short*)alloc(16384 * 2);
  }
  unsigned short* wqh = (unsigned short*)alloc(49152 * 2);
  unsigned short* wql = (unsigned short*)alloc(49152 * 2);
  unsigned short* woh = (unsigned short*)alloc(16384 * 2);
  unsigned short* wol = (unsigned short*)alloc(16384 * 2);

  unsigned short* fhi = (unsigned short*)bufA;
  unsigned short* flo = fhi + (size_t)N_NODES * HID;

  float* fin = (float*)d_out;                       // [N, HID]
  float* emb = fin + (size_t)N_NODES * HID;         // [G, HID]

  hipMemsetAsync(deg, 0, (size_t)N_NODES * 4, stream);
  hist_kernel<<<N_EDGES / 256, 256, 0, stream>>>(dst, deg);
  dis_kernel<<<N_NODES / 256, 256, 0, stream>>>(deg, dis);
  scan_kernel<<<1, 1024, 0, stream>>>(deg, offsets, cursor);
  fill_kernel<<<N_EDGES / 256, 256, 0, stream>>>(src, dst, dis, cursor, csr, wedge);

  wprep_kernel<false><<<4, 256, 0, stream>>>(W0, 64, 128, w0h, w0l);
  for (int i = 0; i < 3; i++)
    wprep_kernel<false><<<8, 256, 0, stream>>>(Wh + (size_t)i * HID * HID, 128, 128,
                                               whh[i], whl[i]);
  wprep_kernel<true><<<24, 256, 0, stream>>>(attn_in_w, 128, 384, wqh, wql);
  wprep_kernel<true><<<8, 256, 0, stream>>>(attn_out_w, 128, 128, woh, wol);

  dim3 ggrid(N_NODES / 128, 1);
  agg64_kernel<<<N_NODES / 4, 256, 0, stream>>>(x, dis, wedge, offsets, csr, zhi, zlo);
  gemm_mfma<64, 128, true, true, false><<<ggrid, 256, 0, stream>>>(
      zhi, zlo, w0h, w0l, b0, bn_gamma, bn_beta, bn_mean, bn_var, bufA, nullptr, nullptr);
  for (int L = 0; L < 2; L++) {
    agg128_kernel<<<N_NODES / 4, 256, 0, stream>>>(bufA, dis, wedge, offsets, csr, zhi, zlo);
    gemm_mfma<128, 128, true, true, false><<<ggrid, 256, 0, stream>>>(
        zhi, zlo, whh[L], whl[L], bh + (size_t)L * HID,
        bn_gamma + (size_t)(L + 1) * HID, bn_beta + (size_t)(L + 1) * HID,
        bn_mean + (size_t)(L + 1) * HID, bn_var + (size_t)(L + 1) * HID,
        bufA, nullptr, nullptr);
  }
  agg128_kernel<<<N_NODES / 4, 256, 0, stream>>>(bufA, dis, wedge, offsets, csr, zhi, zlo);
  gemm_mfma<128, 128, true, true, true><<<ggrid, 256, 0, stream>>>(
      zhi, zlo, whh[2], whl[2], bh + (size_t)2 * HID,
      bn_gamma + (size_t)3 * HID, bn_beta + (size_t)3 * HID,
      bn_mean + (size_t)3 * HID, bn_var + (size_t)3 * HID,
      nullptr, fhi, flo);
  dim3 qgrid(N_NODES / 128, 3);
  gemm_mfma<128, 384, false, false, false><<<qgrid, 256, 0, stream>>>(
      fhi, flo, wqh, wql, attn_in_b, nullptr, nullptr, nullptr, nullptr,
      qkvb, nullptr, nullptr);
  knorm_kernel<<<N_GRAPHS * 4, 256, 0, stream>>>(qkvb, kmax2);
  attn_mfma_kernel<<<N_GRAPHS * 4 * 2, 256, 0, stream>>>(qkvb, kmax2, zhi, zlo);
  gemm_mfma<128, 128, false, false, false><<<ggrid, 256, 0, stream>>>(
      zhi, zlo, woh, wol, attn_out_b, nullptr, nullptr, nullptr, nullptr,
      fin, nullptr, nullptr);
  pool_kernel<<<N_GRAPHS, 128, 0, stream>>>(fin, emb);
}